// Round 1
// baseline (419.605 us; speedup 1.0000x reference)
//
#include <hip/hip_runtime.h>
#include <hip/hip_bf16.h>

// GCN 2-layer + mean-pool + log_softmax on gfx950.
// Pipeline: init -> degree/count atomics -> single-block scan (CSR rowptr)
//   -> rsqrt -> CSR fill -> GEMM1 (bf16 MFMA) -> agg1 (wave/node gather,
//   +b1, relu) -> GEMM2 (fp32) -> agg2 (16 lanes/node) -> pool atomics
//   -> log_softmax.
// CSR avoids 83M fp32 scatter atomics for the 128-wide layer-1 aggregation.

#define NN 50000
#define EE 600000
#define FIN 128
#define HH 128
#define CC 16
#define GG 500
#define ETOT (EE + NN)   // edges + self loops = 650000

typedef unsigned short ushort_t;
typedef unsigned int uint_t;

typedef __attribute__((ext_vector_type(8))) short bf16x8;
typedef __attribute__((ext_vector_type(4))) float f32x4;

__device__ inline ushort_t f2bf(float f) {
    uint_t u = __float_as_uint(f);
    u = (u + 0x7FFFu + ((u >> 16) & 1u)) >> 16;   // RNE
    return (ushort_t)u;
}

// ---------------- init ----------------
__global__ void init_kernel(float* deg, int* cursor, float* counts, float* pooled) {
    int i = blockIdx.x * blockDim.x + threadIdx.x;
    if (i < NN) { deg[i] = 1.0f; cursor[i] = 0; }       // deg starts at 1 (self-loop)
    if (i < GG * CC) pooled[i] = 0.0f;
    if (i < GG) counts[i] = 0.0f;
}

// ---------------- degree + graph counts ----------------
__global__ void degcount_kernel(const int* edge_dst, const int* batch,
                                float* deg, float* counts) {
    int idx = blockIdx.x * blockDim.x + threadIdx.x;
    if (idx < EE) {
        atomicAdd(&deg[edge_dst[idx]], 1.0f);
    } else if (idx < EE + NN) {
        atomicAdd(&counts[batch[idx - EE]], 1.0f);
    }
}

// ---------------- exclusive scan of degrees -> rowptr (single block) ----------------
__global__ void scan_kernel(const float* deg, int* rowptr) {
    __shared__ int sdata[1024];
    int t = threadIdx.x;
    const int PER = (NN + 1023) / 1024;   // 49
    int start = t * PER;
    int end = start + PER; if (end > NN) end = NN;
    int local = 0;
    for (int i = start; i < end; i++) local += (int)(deg[i] + 0.5f);
    sdata[t] = local;
    __syncthreads();
    for (int off = 1; off < 1024; off <<= 1) {
        int v = (t >= off) ? sdata[t - off] : 0;
        __syncthreads();
        sdata[t] += v;
        __syncthreads();
    }
    int run = sdata[t] - local;           // exclusive prefix
    for (int i = start; i < end; i++) {
        rowptr[i] = run;
        run += (int)(deg[i] + 0.5f);
    }
    if (t == 1023) rowptr[NN] = sdata[1023];
}

// ---------------- dis = rsqrt(deg) ----------------
__global__ void dis_kernel(const float* deg, float* dis) {
    int i = blockIdx.x * blockDim.x + threadIdx.x;
    if (i < NN) dis[i] = rsqrtf(deg[i]);
}

// ---------------- CSR fill (edges + self loops) ----------------
__global__ void fill_kernel(const int* edge_src, const int* edge_dst, const float* dis,
                            const int* rowptr, int* cursor, int* csr_src, float* csr_w) {
    int idx = blockIdx.x * blockDim.x + threadIdx.x;
    if (idx >= ETOT) return;
    int s, d;
    if (idx < EE) { s = edge_src[idx]; d = edge_dst[idx]; }
    else          { s = idx - EE; d = s; }
    int pos = rowptr[d] + atomicAdd(&cursor[d], 1);
    csr_src[pos] = s;
    csr_w[pos] = dis[s] * dis[d];
}

// ---------------- GEMM1: h = x @ W1  (bf16 MFMA 16x16x32) ----------------
// Block: 256 threads = 4 waves; tile 64 rows x 128 cols; wave w owns rows 16w..16w+15.
__global__ __launch_bounds__(256) void gemm1_kernel(const float* __restrict__ x,
                                                    const float* __restrict__ W1,
                                                    float* __restrict__ h) {
    __shared__ ushort_t xs[64 * 136];    // x tile, row stride 136 bf16 (bank spread)
    __shared__ ushort_t wt[128 * 136];   // W1 transposed: wt[c][k]
    int t = threadIdx.x;
    int row0 = blockIdx.x * 64;
    for (int i = 0; i < 32; i++) {       // 64*128/256
        int flat = t + i * 256;
        int r = flat >> 7, k = flat & 127;
        int gr = row0 + r;
        float v = (gr < NN) ? x[gr * FIN + k] : 0.0f;
        xs[r * 136 + k] = f2bf(v);
    }
    for (int i = 0; i < 64; i++) {       // 128*128/256
        int flat = t + i * 256;
        int k = flat >> 7, c = flat & 127;
        wt[c * 136 + k] = f2bf(W1[k * HH + c]);
    }
    __syncthreads();

    int wave = t >> 6, lane = t & 63;
    int m = lane & 15, quad = lane >> 4;
    f32x4 acc[8];
    for (int ct = 0; ct < 8; ct++) acc[ct] = (f32x4)(0.0f);

    for (int ko = 0; ko < 4; ko++) {     // K = 128 = 4 * 32
        bf16x8 a = *(const bf16x8*)(&xs[(16 * wave + m) * 136 + ko * 32 + quad * 8]);
        for (int ct = 0; ct < 8; ct++) {
            bf16x8 b = *(const bf16x8*)(&wt[(ct * 16 + m) * 136 + ko * 32 + quad * 8]);
            acc[ct] = __builtin_amdgcn_mfma_f32_16x16x32_bf16(a, b, acc[ct], 0, 0, 0);
        }
    }
    // D layout: col = lane&15, row = quad*4 + reg  [m89-verified]
    for (int ct = 0; ct < 8; ct++) {
        int gcol = ct * 16 + m;
        for (int r = 0; r < 4; r++) {
            int grow = row0 + wave * 16 + quad * 4 + r;
            if (grow < NN) h[grow * HH + gcol] = acc[ct][r];
        }
    }
}

// ---------------- agg1: h1 = relu(segment_sum(norm * h[src]) + b1), wave/node ----------------
__global__ __launch_bounds__(256) void agg1_kernel(const float* __restrict__ h,
                                                   const int* __restrict__ rowptr,
                                                   const int* __restrict__ csr_src,
                                                   const float* __restrict__ csr_w,
                                                   const float* __restrict__ b1,
                                                   float* __restrict__ h1) {
    int wave = threadIdx.x >> 6, lane = threadIdx.x & 63;
    int node = blockIdx.x * 4 + wave;
    if (node >= NN) return;
    int e0 = rowptr[node], e1 = rowptr[node + 1];
    float a0 = 0.0f, a1 = 0.0f;
    for (int e = e0; e < e1; e++) {
        int s = csr_src[e];
        float w = csr_w[e];
        float2 hv = *(const float2*)(h + s * HH + lane * 2);
        a0 += w * hv.x;
        a1 += w * hv.y;
    }
    float v0 = a0 + b1[lane * 2];
    float v1 = a1 + b1[lane * 2 + 1];
    h1[node * HH + lane * 2]     = fmaxf(v0, 0.0f);
    h1[node * HH + lane * 2 + 1] = fmaxf(v1, 0.0f);
}

// ---------------- GEMM2: h2 = h1 @ W2  (fp32, 16 cols) ----------------
__global__ __launch_bounds__(256) void gemm2_kernel(const float* __restrict__ h1,
                                                    const float* __restrict__ W2,
                                                    float* __restrict__ h2) {
    __shared__ float w2s[HH * CC];
    int t = threadIdx.x;
    for (int i = t; i < HH * CC; i += 256) w2s[i] = W2[i];
    __syncthreads();
    int col = t & 15, rg = t >> 4;
    int row = blockIdx.x * 16 + rg;
    if (row >= NN) return;
    const float4* hr = (const float4*)(h1 + row * HH);
    float acc = 0.0f;
    for (int k4 = 0; k4 < HH / 4; k4++) {
        float4 hv = hr[k4];
        int k = k4 * 4;
        acc += hv.x * w2s[k * CC + col];
        acc += hv.y * w2s[(k + 1) * CC + col];
        acc += hv.z * w2s[(k + 2) * CC + col];
        acc += hv.w * w2s[(k + 3) * CC + col];
    }
    h2[row * CC + col] = acc;
}

// ---------------- agg2: a2 = segment_sum(norm * h2[src]) + b2 (16 lanes/node) ----------------
__global__ __launch_bounds__(256) void agg2_kernel(const float* __restrict__ h2,
                                                   const int* __restrict__ rowptr,
                                                   const int* __restrict__ csr_src,
                                                   const float* __restrict__ csr_w,
                                                   const float* __restrict__ b2,
                                                   float* __restrict__ a2) {
    int idx = blockIdx.x * blockDim.x + threadIdx.x;
    int node = idx >> 4, c = idx & 15;
    if (node >= NN) return;
    int e0 = rowptr[node], e1 = rowptr[node + 1];
    float acc = 0.0f;
    for (int e = e0; e < e1; e++) {
        acc += csr_w[e] * h2[csr_src[e] * CC + c];
    }
    a2[node * CC + c] = acc + b2[c];
}

// ---------------- pooling: scatter-add into pooled[g][c] ----------------
__global__ void pool_kernel(const float* __restrict__ a2, const int* __restrict__ batch,
                            float* __restrict__ pooled) {
    int idx = blockIdx.x * blockDim.x + threadIdx.x;
    int node = idx >> 4, c = idx & 15;
    if (node >= NN) return;
    atomicAdd(&pooled[batch[node] * CC + c], a2[node * CC + c]);
}

// ---------------- mean + log_softmax ----------------
__global__ void lsm_kernel(const float* __restrict__ pooled, const float* __restrict__ counts,
                           float* __restrict__ out) {
    int idx = blockIdx.x * blockDim.x + threadIdx.x;
    int g = idx >> 4, c = idx & 15;
    if (g >= GG) return;
    float v = pooled[g * CC + c] / fmaxf(counts[g], 1.0f);
    float m = v;
    for (int off = 8; off >= 1; off >>= 1) m = fmaxf(m, __shfl_xor(m, off, 16));
    float s = expf(v - m);
    for (int off = 8; off >= 1; off >>= 1) s += __shfl_xor(s, off, 16);
    out[g * CC + c] = v - m - logf(s);
}

extern "C" void kernel_launch(void* const* d_in, const int* in_sizes, int n_in,
                              void* d_out, int out_size, void* d_ws, size_t ws_size,
                              hipStream_t stream) {
    const float* x  = (const float*)d_in[0];
    const float* W1 = (const float*)d_in[1];
    const float* b1 = (const float*)d_in[2];
    const float* W2 = (const float*)d_in[3];
    const float* b2 = (const float*)d_in[4];
    const int* edge_src = (const int*)d_in[5];
    const int* edge_dst = (const int*)d_in[6];
    const int* batch    = (const int*)d_in[7];
    float* out = (float*)d_out;

    char* ws = (char*)d_ws;
    size_t off = 0;
    auto alloc = [&](size_t bytes) {
        void* p = ws + off;
        off += (bytes + 255) & ~size_t(255);
        return p;
    };
    float* deg     = (float*)alloc(NN * 4);
    float* dis     = (float*)alloc(NN * 4);
    int*   rowptr  = (int*)  alloc((NN + 1) * 4);
    int*   cursor  = (int*)  alloc(NN * 4);
    int*   csr_src = (int*)  alloc(ETOT * 4);
    float* csr_w   = (float*)alloc(ETOT * 4);
    float* h       = (float*)alloc((size_t)NN * HH * 4);
    float* h1      = (float*)alloc((size_t)NN * HH * 4);
    float* h2      = (float*)alloc((size_t)NN * CC * 4);
    float* a2      = (float*)alloc((size_t)NN * CC * 4);
    float* counts  = (float*)alloc(GG * 4);
    float* pooled  = (float*)alloc(GG * CC * 4);

    const int B = 256;
    init_kernel<<<(NN + B - 1) / B, B, 0, stream>>>(deg, cursor, counts, pooled);
    degcount_kernel<<<(ETOT + B - 1) / B, B, 0, stream>>>(edge_dst, batch, deg, counts);
    scan_kernel<<<1, 1024, 0, stream>>>(deg, rowptr);
    dis_kernel<<<(NN + B - 1) / B, B, 0, stream>>>(deg, dis);
    fill_kernel<<<(ETOT + B - 1) / B, B, 0, stream>>>(edge_src, edge_dst, dis,
                                                      rowptr, cursor, csr_src, csr_w);
    gemm1_kernel<<<(NN + 63) / 64, B, 0, stream>>>(x, W1, h);
    agg1_kernel<<<(NN + 3) / 4, B, 0, stream>>>(h, rowptr, csr_src, csr_w, b1, h1);
    gemm2_kernel<<<(NN + 15) / 16, B, 0, stream>>>(h1, W2, h2);
    agg2_kernel<<<(NN * CC + B - 1) / B, B, 0, stream>>>(h2, rowptr, csr_src, csr_w, b2, a2);
    pool_kernel<<<(NN * CC + B - 1) / B, B, 0, stream>>>(a2, batch, pooled);
    lsm_kernel<<<(GG * CC + B - 1) / B, B, 0, stream>>>(pooled, counts, out);
}

// Round 2
// 338.316 us; speedup vs baseline: 1.2403x; 1.2403x over previous
//
#include <hip/hip_runtime.h>
#include <hip/hip_bf16.h>

// GCN 2-layer + mean-pool + log_softmax on gfx950.
// R2: two-level parallel scan (replaces 77us single-block scan), int degree
//     atomics, dis fused into scanA, pool fused into agg2.

#define NN 50000
#define EE 600000
#define FIN 128
#define HH 128
#define CC 16
#define GG 500
#define ETOT (EE + NN)   // edges + self loops = 650000
#define SBLK 196         // ceil(NN/256) scan blocks

typedef unsigned short ushort_t;
typedef unsigned int uint_t;

typedef __attribute__((ext_vector_type(8))) short bf16x8;
typedef __attribute__((ext_vector_type(4))) float f32x4;

__device__ inline ushort_t f2bf(float f) {
    uint_t u = __float_as_uint(f);
    u = (u + 0x7FFFu + ((u >> 16) & 1u)) >> 16;   // RNE
    return (ushort_t)u;
}

// ---------------- init ----------------
__global__ void init_kernel(int* degi, int* cursor, float* counts, float* pooled) {
    int i = blockIdx.x * blockDim.x + threadIdx.x;
    if (i < NN) { degi[i] = 0; cursor[i] = 0; }
    if (i < GG * CC) pooled[i] = 0.0f;
    if (i < GG) counts[i] = 0.0f;
}

// ---------------- degree + graph counts ----------------
__global__ void degcount_kernel(const int* edge_dst, const int* batch,
                                int* degi, float* counts) {
    int idx = blockIdx.x * blockDim.x + threadIdx.x;
    if (idx < EE) {
        atomicAdd(&degi[edge_dst[idx]], 1);
    } else if (idx < EE + NN) {
        atomicAdd(&counts[batch[idx - EE]], 1.0f);
    }
}

// ---------------- block-scan helper: inclusive scan of v across 256 threads ----
// returns exclusive prefix; *total gets block sum
__device__ inline int block_excl_scan(int v, int t, int* total) {
    __shared__ int wsum[4];
    int lane = t & 63, wv = t >> 6;
    int inc = v;
    for (int off = 1; off < 64; off <<= 1) {
        int n = __shfl_up(inc, off);
        if (lane >= off) inc += n;
    }
    if (lane == 63) wsum[wv] = inc;
    __syncthreads();
    int off_w = 0;
    for (int w = 0; w < wv; w++) off_w += wsum[w];
    *total = wsum[0] + wsum[1] + wsum[2] + wsum[3];
    return off_w + inc - v;
}

// ---------------- scan phase A: per-block exclusive scan + dis ----------------
__global__ __launch_bounds__(256) void scanA_kernel(const int* __restrict__ degi,
                                                    int* __restrict__ rowptr,
                                                    float* __restrict__ dis,
                                                    int* __restrict__ bsum) {
    int t = threadIdx.x;
    int i = blockIdx.x * 256 + t;
    int d = 0;
    if (i < NN) {
        d = degi[i] + 1;                       // +1 self-loop
        dis[i] = rsqrtf((float)d);
    }
    int total;
    int excl = block_excl_scan(d, t, &total);
    if (i < NN) rowptr[i] = excl;
    if (t == 0) bsum[blockIdx.x] = total;
}

// ---------------- scan phase B: scan block sums (single block) ----------------
__global__ __launch_bounds__(256) void scanB_kernel(const int* __restrict__ bsum,
                                                    int* __restrict__ boff,
                                                    int* __restrict__ rowptr) {
    int t = threadIdx.x;
    int v = (t < SBLK) ? bsum[t] : 0;
    int total;
    int excl = block_excl_scan(v, t, &total);
    if (t < SBLK) boff[t] = excl;
    if (t == 0) rowptr[NN] = total;            // = ETOT
}

// ---------------- scan phase C: add block offsets ----------------
__global__ __launch_bounds__(256) void scanC_kernel(int* __restrict__ rowptr,
                                                    const int* __restrict__ boff) {
    int i = blockIdx.x * 256 + threadIdx.x;
    if (i < NN) rowptr[i] += boff[blockIdx.x];
}

// ---------------- CSR fill (edges + self loops) ----------------
__global__ void fill_kernel(const int* edge_src, const int* edge_dst, const float* dis,
                            const int* rowptr, int* cursor, int* csr_src, float* csr_w) {
    int idx = blockIdx.x * blockDim.x + threadIdx.x;
    if (idx >= ETOT) return;
    int s, d;
    if (idx < EE) { s = edge_src[idx]; d = edge_dst[idx]; }
    else          { s = idx - EE; d = s; }
    int pos = rowptr[d] + atomicAdd(&cursor[d], 1);
    csr_src[pos] = s;
    csr_w[pos] = dis[s] * dis[d];
}

// ---------------- GEMM1: h = x @ W1  (bf16 MFMA 16x16x32) ----------------
__global__ __launch_bounds__(256) void gemm1_kernel(const float* __restrict__ x,
                                                    const float* __restrict__ W1,
                                                    float* __restrict__ h) {
    __shared__ ushort_t xs[64 * 136];
    __shared__ ushort_t wt[128 * 136];
    int t = threadIdx.x;
    int row0 = blockIdx.x * 64;
    for (int i = 0; i < 32; i++) {
        int flat = t + i * 256;
        int r = flat >> 7, k = flat & 127;
        int gr = row0 + r;
        float v = (gr < NN) ? x[gr * FIN + k] : 0.0f;
        xs[r * 136 + k] = f2bf(v);
    }
    for (int i = 0; i < 64; i++) {
        int flat = t + i * 256;
        int k = flat >> 7, c = flat & 127;
        wt[c * 136 + k] = f2bf(W1[k * HH + c]);
    }
    __syncthreads();

    int wave = t >> 6, lane = t & 63;
    int m = lane & 15, quad = lane >> 4;
    f32x4 acc[8];
    for (int ct = 0; ct < 8; ct++) acc[ct] = (f32x4)(0.0f);

    for (int ko = 0; ko < 4; ko++) {
        bf16x8 a = *(const bf16x8*)(&xs[(16 * wave + m) * 136 + ko * 32 + quad * 8]);
        for (int ct = 0; ct < 8; ct++) {
            bf16x8 b = *(const bf16x8*)(&wt[(ct * 16 + m) * 136 + ko * 32 + quad * 8]);
            acc[ct] = __builtin_amdgcn_mfma_f32_16x16x32_bf16(a, b, acc[ct], 0, 0, 0);
        }
    }
    for (int ct = 0; ct < 8; ct++) {
        int gcol = ct * 16 + m;
        for (int r = 0; r < 4; r++) {
            int grow = row0 + wave * 16 + quad * 4 + r;
            if (grow < NN) h[grow * HH + gcol] = acc[ct][r];
        }
    }
}

// ---------------- agg1: h1 = relu(segment_sum(norm * h[src]) + b1), wave/node ----
__global__ __launch_bounds__(256) void agg1_kernel(const float* __restrict__ h,
                                                   const int* __restrict__ rowptr,
                                                   const int* __restrict__ csr_src,
                                                   const float* __restrict__ csr_w,
                                                   const float* __restrict__ b1,
                                                   float* __restrict__ h1) {
    int wave = threadIdx.x >> 6, lane = threadIdx.x & 63;
    int node = blockIdx.x * 4 + wave;
    if (node >= NN) return;
    int e0 = rowptr[node], e1 = rowptr[node + 1];
    float a0 = 0.0f, a1 = 0.0f;
    for (int e = e0; e < e1; e++) {
        int s = csr_src[e];
        float w = csr_w[e];
        float2 hv = *(const float2*)(h + s * HH + lane * 2);
        a0 += w * hv.x;
        a1 += w * hv.y;
    }
    float v0 = a0 + b1[lane * 2];
    float v1 = a1 + b1[lane * 2 + 1];
    h1[node * HH + lane * 2]     = fmaxf(v0, 0.0f);
    h1[node * HH + lane * 2 + 1] = fmaxf(v1, 0.0f);
}

// ---------------- GEMM2: h2 = h1 @ W2  (fp32, 16 cols) ----------------
__global__ __launch_bounds__(256) void gemm2_kernel(const float* __restrict__ h1,
                                                    const float* __restrict__ W2,
                                                    float* __restrict__ h2) {
    __shared__ float w2s[HH * CC];
    int t = threadIdx.x;
    for (int i = t; i < HH * CC; i += 256) w2s[i] = W2[i];
    __syncthreads();
    int col = t & 15, rg = t >> 4;
    int row = blockIdx.x * 16 + rg;
    if (row >= NN) return;
    const float4* hr = (const float4*)(h1 + row * HH);
    float acc = 0.0f;
    for (int k4 = 0; k4 < HH / 4; k4++) {
        float4 hv = hr[k4];
        int k = k4 * 4;
        acc += hv.x * w2s[k * CC + col];
        acc += hv.y * w2s[(k + 1) * CC + col];
        acc += hv.z * w2s[(k + 2) * CC + col];
        acc += hv.w * w2s[(k + 3) * CC + col];
    }
    h2[row * CC + col] = acc;
}

// ---------------- agg2 + pool fused: pooled[g][c] += segsum(norm*h2[src]) + b2 ----
__global__ void agg2pool_kernel(const float* __restrict__ h2,
                                const int* __restrict__ rowptr,
                                const int* __restrict__ csr_src,
                                const float* __restrict__ csr_w,
                                const float* __restrict__ b2,
                                const int* __restrict__ batch,
                                float* __restrict__ pooled) {
    int idx = blockIdx.x * blockDim.x + threadIdx.x;
    int node = idx >> 4, c = idx & 15;
    if (node >= NN) return;
    int e0 = rowptr[node], e1 = rowptr[node + 1];
    float acc = 0.0f;
    for (int e = e0; e < e1; e++) {
        acc += csr_w[e] * h2[csr_src[e] * CC + c];
    }
    atomicAdd(&pooled[batch[node] * CC + c], acc + b2[c]);
}

// ---------------- mean + log_softmax ----------------
__global__ void lsm_kernel(const float* __restrict__ pooled, const float* __restrict__ counts,
                           float* __restrict__ out) {
    int idx = blockIdx.x * blockDim.x + threadIdx.x;
    int g = idx >> 4, c = idx & 15;
    if (g >= GG) return;
    float v = pooled[g * CC + c] / fmaxf(counts[g], 1.0f);
    float m = v;
    for (int off = 8; off >= 1; off >>= 1) m = fmaxf(m, __shfl_xor(m, off, 16));
    float s = expf(v - m);
    for (int off = 8; off >= 1; off >>= 1) s += __shfl_xor(s, off, 16);
    out[g * CC + c] = v - m - logf(s);
}

extern "C" void kernel_launch(void* const* d_in, const int* in_sizes, int n_in,
                              void* d_out, int out_size, void* d_ws, size_t ws_size,
                              hipStream_t stream) {
    const float* x  = (const float*)d_in[0];
    const float* W1 = (const float*)d_in[1];
    const float* b1 = (const float*)d_in[2];
    const float* W2 = (const float*)d_in[3];
    const float* b2 = (const float*)d_in[4];
    const int* edge_src = (const int*)d_in[5];
    const int* edge_dst = (const int*)d_in[6];
    const int* batch    = (const int*)d_in[7];
    float* out = (float*)d_out;

    char* ws = (char*)d_ws;
    size_t off = 0;
    auto alloc = [&](size_t bytes) {
        void* p = ws + off;
        off += (bytes + 255) & ~size_t(255);
        return p;
    };
    int*   degi    = (int*)  alloc(NN * 4);
    float* dis     = (float*)alloc(NN * 4);
    int*   rowptr  = (int*)  alloc((NN + 1) * 4);
    int*   cursor  = (int*)  alloc(NN * 4);
    int*   bsum    = (int*)  alloc(SBLK * 4);
    int*   boff    = (int*)  alloc(SBLK * 4);
    int*   csr_src = (int*)  alloc(ETOT * 4);
    float* csr_w   = (float*)alloc(ETOT * 4);
    float* h       = (float*)alloc((size_t)NN * HH * 4);
    float* h1      = (float*)alloc((size_t)NN * HH * 4);
    float* h2      = (float*)alloc((size_t)NN * CC * 4);
    float* counts  = (float*)alloc(GG * 4);
    float* pooled  = (float*)alloc(GG * CC * 4);

    const int B = 256;
    init_kernel<<<(NN + B - 1) / B, B, 0, stream>>>(degi, cursor, counts, pooled);
    degcount_kernel<<<(ETOT + B - 1) / B, B, 0, stream>>>(edge_dst, batch, degi, counts);
    scanA_kernel<<<SBLK, B, 0, stream>>>(degi, rowptr, dis, bsum);
    scanB_kernel<<<1, B, 0, stream>>>(bsum, boff, rowptr);
    scanC_kernel<<<SBLK, B, 0, stream>>>(rowptr, boff);
    fill_kernel<<<(ETOT + B - 1) / B, B, 0, stream>>>(edge_src, edge_dst, dis,
                                                      rowptr, cursor, csr_src, csr_w);
    gemm1_kernel<<<(NN + 63) / 64, B, 0, stream>>>(x, W1, h);
    agg1_kernel<<<(NN + 3) / 4, B, 0, stream>>>(h, rowptr, csr_src, csr_w, b1, h1);
    gemm2_kernel<<<(NN + 15) / 16, B, 0, stream>>>(h1, W2, h2);
    agg2pool_kernel<<<(NN * CC + B - 1) / B, B, 0, stream>>>(h2, rowptr, csr_src, csr_w,
                                                             b2, batch, pooled);
    lsm_kernel<<<(GG * CC + B - 1) / B, B, 0, stream>>>(pooled, counts, out);
}

// Round 3
// 281.946 us; speedup vs baseline: 1.4882x; 1.1999x over previous
//
#include <hip/hip_runtime.h>
#include <hip/hip_bf16.h>

// GCN 2-layer + mean-pool + log_softmax on gfx950.
// R3: bf16 h/h1 (halves the random gather), edge-slot agg1 (4 chains/wave),
//     MFMA gemm2, packed int2 CSR, cursor=rowptr (no rowptr read in fill).

#define NN 50000
#define EE 600000
#define FIN 128
#define HH 128
#define CC 16
#define GG 500
#define ETOT (EE + NN)   // edges + self loops = 650000
#define SBLK 196         // ceil(NN/256) scan blocks

typedef unsigned short ushort_t;
typedef unsigned int uint_t;

typedef __attribute__((ext_vector_type(8))) short bf16x8;
typedef __attribute__((ext_vector_type(8))) ushort_t u16x8;
typedef __attribute__((ext_vector_type(4))) ushort_t u16x4;
typedef __attribute__((ext_vector_type(4))) float f32x4;

__device__ inline ushort_t f2bf(float f) {
    uint_t u = __float_as_uint(f);
    u = (u + 0x7FFFu + ((u >> 16) & 1u)) >> 16;   // RNE
    return (ushort_t)u;
}
__device__ inline float bf2f(ushort_t b) {
    return __uint_as_float(((uint_t)b) << 16);
}

// ---------------- init ----------------
__global__ void init_kernel(int* degi, float* counts, float* pooled) {
    int i = blockIdx.x * blockDim.x + threadIdx.x;
    if (i < NN) degi[i] = 0;
    if (i < GG * CC) pooled[i] = 0.0f;
    if (i < GG) counts[i] = 0.0f;
}

// ---------------- degree + graph counts ----------------
__global__ void degcount_kernel(const int* edge_dst, const int* batch,
                                int* degi, float* counts) {
    int idx = blockIdx.x * blockDim.x + threadIdx.x;
    if (idx < EE) {
        atomicAdd(&degi[edge_dst[idx]], 1);
    } else if (idx < EE + NN) {
        atomicAdd(&counts[batch[idx - EE]], 1.0f);
    }
}

// ---------------- block-scan helper ----------------
__device__ inline int block_excl_scan(int v, int t, int* total) {
    __shared__ int wsum[4];
    int lane = t & 63, wv = t >> 6;
    int inc = v;
    for (int off = 1; off < 64; off <<= 1) {
        int n = __shfl_up(inc, off);
        if (lane >= off) inc += n;
    }
    if (lane == 63) wsum[wv] = inc;
    __syncthreads();
    int off_w = 0;
    for (int w = 0; w < wv; w++) off_w += wsum[w];
    *total = wsum[0] + wsum[1] + wsum[2] + wsum[3];
    return off_w + inc - v;
}

// ---------------- scan A: per-block exclusive scan + dis ----------------
__global__ __launch_bounds__(256) void scanA_kernel(const int* __restrict__ degi,
                                                    int* __restrict__ rowptr,
                                                    float* __restrict__ dis,
                                                    int* __restrict__ bsum) {
    int t = threadIdx.x;
    int i = blockIdx.x * 256 + t;
    int d = 0;
    if (i < NN) {
        d = degi[i] + 1;                       // +1 self-loop
        dis[i] = rsqrtf((float)d);
    }
    int total;
    int excl = block_excl_scan(d, t, &total);
    if (i < NN) rowptr[i] = excl;
    if (t == 0) bsum[blockIdx.x] = total;
}

// ---------------- scan B: scan block sums ----------------
__global__ __launch_bounds__(256) void scanB_kernel(const int* __restrict__ bsum,
                                                    int* __restrict__ boff,
                                                    int* __restrict__ rowptr) {
    int t = threadIdx.x;
    int v = (t < SBLK) ? bsum[t] : 0;
    int total;
    int excl = block_excl_scan(v, t, &total);
    if (t < SBLK) boff[t] = excl;
    if (t == 0) rowptr[NN] = total;
}

// ---------------- scan C: add block offsets; cursor = rowptr ----------------
__global__ __launch_bounds__(256) void scanC_kernel(int* __restrict__ rowptr,
                                                    const int* __restrict__ boff,
                                                    int* __restrict__ cursor) {
    int i = blockIdx.x * 256 + threadIdx.x;
    if (i < NN) {
        int r = rowptr[i] + boff[blockIdx.x];
        rowptr[i] = r;
        cursor[i] = r;
    }
}

// ---------------- CSR fill: packed (src, w) int2, single 8B scattered store ----
__global__ void fill_kernel(const int* edge_src, const int* edge_dst, const float* dis,
                            int* cursor, int2* csr) {
    int idx = blockIdx.x * blockDim.x + threadIdx.x;
    if (idx >= ETOT) return;
    int s, d;
    if (idx < EE) { s = edge_src[idx]; d = edge_dst[idx]; }
    else          { s = idx - EE; d = s; }
    int pos = atomicAdd(&cursor[d], 1);
    csr[pos] = make_int2(s, __float_as_int(dis[s] * dis[d]));
}

// ---------------- GEMM1: hb = bf16(x @ W1)  (bf16 MFMA 16x16x32) ----------------
__global__ __launch_bounds__(256) void gemm1_kernel(const float* __restrict__ x,
                                                    const float* __restrict__ W1,
                                                    ushort_t* __restrict__ hb) {
    __shared__ ushort_t xs[64 * 136];
    __shared__ ushort_t wt[128 * 136];
    int t = threadIdx.x;
    int row0 = blockIdx.x * 64;
    // stage x tile: 64 rows x 32 float4
    for (int i = 0; i < 8; i++) {
        int slot = t + i * 256;
        int r = slot >> 5, k4 = slot & 31;
        int gr = row0 + r;
        float4 v = (gr < NN) ? ((const float4*)x)[gr * 32 + k4]
                             : make_float4(0.f, 0.f, 0.f, 0.f);
        u16x4 bv = { f2bf(v.x), f2bf(v.y), f2bf(v.z), f2bf(v.w) };
        *(u16x4*)(&xs[r * 136 + k4 * 4]) = bv;
    }
    // stage W1 transposed: wt[c][k]
    for (int i = 0; i < 16; i++) {
        int slot = t + i * 256;
        int k = slot >> 5, c4 = slot & 31;
        float4 v = ((const float4*)W1)[k * 32 + c4];
        wt[(c4 * 4 + 0) * 136 + k] = f2bf(v.x);
        wt[(c4 * 4 + 1) * 136 + k] = f2bf(v.y);
        wt[(c4 * 4 + 2) * 136 + k] = f2bf(v.z);
        wt[(c4 * 4 + 3) * 136 + k] = f2bf(v.w);
    }
    __syncthreads();

    int wave = t >> 6, lane = t & 63;
    int m = lane & 15, quad = lane >> 4;
    f32x4 acc[8];
    for (int ct = 0; ct < 8; ct++) acc[ct] = (f32x4)(0.0f);

    for (int ko = 0; ko < 4; ko++) {
        bf16x8 a = *(const bf16x8*)(&xs[(16 * wave + m) * 136 + ko * 32 + quad * 8]);
        for (int ct = 0; ct < 8; ct++) {
            bf16x8 b = *(const bf16x8*)(&wt[(ct * 16 + m) * 136 + ko * 32 + quad * 8]);
            acc[ct] = __builtin_amdgcn_mfma_f32_16x16x32_bf16(a, b, acc[ct], 0, 0, 0);
        }
    }
    // D: col = lane&15, row = quad*4 + reg
    for (int ct = 0; ct < 8; ct++) {
        int gcol = ct * 16 + m;
        for (int r = 0; r < 4; r++) {
            int grow = row0 + wave * 16 + quad * 4 + r;
            if (grow < NN) hb[grow * HH + gcol] = f2bf(acc[ct][r]);
        }
    }
}

// ---------------- agg1: h1b = bf16(relu(segsum(w * hb[src]) + b1)) -------------
// 1 wave per node; 4 edge slots x 16 feature-lanes (bf16x8 = 16B/lane).
__global__ __launch_bounds__(256) void agg1_kernel(const ushort_t* __restrict__ hb,
                                                   const int* __restrict__ rowptr,
                                                   const int2* __restrict__ csr,
                                                   const float* __restrict__ b1,
                                                   ushort_t* __restrict__ h1b) {
    int wave = threadIdx.x >> 6, lane = threadIdx.x & 63;
    int node = blockIdx.x * 4 + wave;
    if (node >= NN) return;
    int slot = lane >> 4, sub = lane & 15;
    int e0 = rowptr[node], e1 = rowptr[node + 1];
    float acc[8] = {0, 0, 0, 0, 0, 0, 0, 0};
    for (int e = e0 + slot; e < e1; e += 4) {
        int2 ent = csr[e];
        float w = __int_as_float(ent.y);
        u16x8 hv = *(const u16x8*)(hb + (size_t)ent.x * HH + sub * 8);
        for (int j = 0; j < 8; j++) acc[j] += w * bf2f(hv[j]);
    }
    // reduce the 4 slots
    for (int j = 0; j < 8; j++) {
        acc[j] += __shfl_xor(acc[j], 16);
        acc[j] += __shfl_xor(acc[j], 32);
    }
    if (slot == 0) {
        u16x8 o;
        for (int j = 0; j < 8; j++)
            o[j] = f2bf(fmaxf(acc[j] + b1[sub * 8 + j], 0.0f));
        *(u16x8*)(h1b + (size_t)node * HH + sub * 8) = o;
    }
}

// ---------------- GEMM2: h2 = h1b @ W2  (bf16 MFMA, 16 cols) ----------------
// 4 waves/block, 16 rows/wave, K=128 in 4 MFMAs.
__global__ __launch_bounds__(256) void gemm2_kernel(const ushort_t* __restrict__ h1b,
                                                    const float* __restrict__ W2,
                                                    float* __restrict__ h2) {
    __shared__ ushort_t w2s[HH * CC];   // bf16, [k][n]
    int t = threadIdx.x;
    for (int i = t; i < HH * CC; i += 256) w2s[i] = f2bf(W2[i]);
    __syncthreads();
    int wave = t >> 6, lane = t & 63;
    int m = lane & 15, quad = lane >> 4;
    int node0 = (blockIdx.x * 4 + wave) * 16;
    f32x4 acc = (f32x4)(0.0f);
    int arow = node0 + m;
    for (int ko = 0; ko < 4; ko++) {
        bf16x8 a = (bf16x8)(short)0;
        if (arow < NN)
            a = *(const bf16x8*)(h1b + (size_t)arow * HH + ko * 32 + quad * 8);
        bf16x8 b;
        for (int j = 0; j < 8; j++)
            b[j] = (short)w2s[(ko * 32 + quad * 8 + j) * CC + m];
        acc = __builtin_amdgcn_mfma_f32_16x16x32_bf16(a, b, acc, 0, 0, 0);
    }
    for (int r = 0; r < 4; r++) {
        int grow = node0 + quad * 4 + r;
        if (grow < NN) h2[grow * CC + m] = acc[r];
    }
}

// ---------------- agg2 + pool fused ----------------
__global__ void agg2pool_kernel(const float* __restrict__ h2,
                                const int* __restrict__ rowptr,
                                const int2* __restrict__ csr,
                                const float* __restrict__ b2,
                                const int* __restrict__ batch,
                                float* __restrict__ pooled) {
    int idx = blockIdx.x * blockDim.x + threadIdx.x;
    int node = idx >> 4, c = idx & 15;
    if (node >= NN) return;
    int e0 = rowptr[node], e1 = rowptr[node + 1];
    float acc = 0.0f;
    for (int e = e0; e < e1; e++) {
        int2 ent = csr[e];
        acc += __int_as_float(ent.y) * h2[(size_t)ent.x * CC + c];
    }
    atomicAdd(&pooled[batch[node] * CC + c], acc + b2[c]);
}

// ---------------- mean + log_softmax ----------------
__global__ void lsm_kernel(const float* __restrict__ pooled, const float* __restrict__ counts,
                           float* __restrict__ out) {
    int idx = blockIdx.x * blockDim.x + threadIdx.x;
    int g = idx >> 4, c = idx & 15;
    if (g >= GG) return;
    float v = pooled[g * CC + c] / fmaxf(counts[g], 1.0f);
    float m = v;
    for (int off = 8; off >= 1; off >>= 1) m = fmaxf(m, __shfl_xor(m, off, 16));
    float s = expf(v - m);
    for (int off = 8; off >= 1; off >>= 1) s += __shfl_xor(s, off, 16);
    out[g * CC + c] = v - m - logf(s);
}

extern "C" void kernel_launch(void* const* d_in, const int* in_sizes, int n_in,
                              void* d_out, int out_size, void* d_ws, size_t ws_size,
                              hipStream_t stream) {
    const float* x  = (const float*)d_in[0];
    const float* W1 = (const float*)d_in[1];
    const float* b1 = (const float*)d_in[2];
    const float* W2 = (const float*)d_in[3];
    const float* b2 = (const float*)d_in[4];
    const int* edge_src = (const int*)d_in[5];
    const int* edge_dst = (const int*)d_in[6];
    const int* batch    = (const int*)d_in[7];
    float* out = (float*)d_out;

    char* ws = (char*)d_ws;
    size_t off = 0;
    auto alloc = [&](size_t bytes) {
        void* p = ws + off;
        off += (bytes + 255) & ~size_t(255);
        return p;
    };
    int*   degi    = (int*)  alloc(NN * 4);
    float* dis     = (float*)alloc(NN * 4);
    int*   rowptr  = (int*)  alloc((NN + 1) * 4);
    int*   cursor  = (int*)  alloc(NN * 4);
    int*   bsum    = (int*)  alloc(SBLK * 4);
    int*   boff    = (int*)  alloc(SBLK * 4);
    int2*  csr     = (int2*) alloc((size_t)ETOT * 8);
    ushort_t* hb   = (ushort_t*)alloc((size_t)NN * HH * 2);
    ushort_t* h1b  = (ushort_t*)alloc((size_t)NN * HH * 2);
    float* h2      = (float*)alloc((size_t)NN * CC * 4);
    float* counts  = (float*)alloc(GG * 4);
    float* pooled  = (float*)alloc(GG * CC * 4);

    const int B = 256;
    init_kernel<<<(NN + B - 1) / B, B, 0, stream>>>(degi, counts, pooled);
    degcount_kernel<<<(ETOT + B - 1) / B, B, 0, stream>>>(edge_dst, batch, degi, counts);
    scanA_kernel<<<SBLK, B, 0, stream>>>(degi, rowptr, dis, bsum);
    scanB_kernel<<<1, B, 0, stream>>>(bsum, boff, rowptr);
    scanC_kernel<<<SBLK, B, 0, stream>>>(rowptr, boff, cursor);
    fill_kernel<<<(ETOT + B - 1) / B, B, 0, stream>>>(edge_src, edge_dst, dis, cursor, csr);
    gemm1_kernel<<<(NN + 63) / 64, B, 0, stream>>>(x, W1, hb);
    agg1_kernel<<<(NN + 3) / 4, B, 0, stream>>>(hb, rowptr, csr, b1, h1b);
    gemm2_kernel<<<(NN + 63) / 64, B, 0, stream>>>(h1b, W2, h2);
    agg2pool_kernel<<<(NN * CC + B - 1) / B, B, 0, stream>>>(h2, rowptr, csr, b2, batch, pooled);
    lsm_kernel<<<(GG * CC + B - 1) / B, B, 0, stream>>>(pooled, counts, out);
}

// Round 4
// 231.258 us; speedup vs baseline: 1.8144x; 1.2192x over previous
//
#include <hip/hip_runtime.h>
#include <hip/hip_bf16.h>

// GCN 2-layer + mean-pool + log_softmax on gfx950.
// R4: single atomic pass (count+seq), atomic-free CSR fill (self-loop at
//     row end), graph counts via binary search in lsm (no hot atomics).

#define NN 50000
#define EE 600000
#define FIN 128
#define HH 128
#define CC 16
#define GG 500
#define ETOT (EE + NN)   // edges + self loops = 650000
#define SBLK 196         // ceil(NN/256) scan blocks

typedef unsigned short ushort_t;
typedef unsigned int uint_t;

typedef __attribute__((ext_vector_type(8))) short bf16x8;
typedef __attribute__((ext_vector_type(8))) ushort_t u16x8;
typedef __attribute__((ext_vector_type(4))) ushort_t u16x4;
typedef __attribute__((ext_vector_type(4))) float f32x4;

__device__ inline ushort_t f2bf(float f) {
    uint_t u = __float_as_uint(f);
    u = (u + 0x7FFFu + ((u >> 16) & 1u)) >> 16;   // RNE
    return (ushort_t)u;
}
__device__ inline float bf2f(ushort_t b) {
    return __uint_as_float(((uint_t)b) << 16);
}

// ---------------- init ----------------
__global__ void init_kernel(int* cnt, float* pooled) {
    int i = blockIdx.x * blockDim.x + threadIdx.x;
    if (i < NN) cnt[i] = 0;
    if (i < GG * CC) pooled[i] = 0.0f;
}

// ---------------- count + per-edge slot (the single atomic pass) ----------------
__global__ void count_kernel(const int* __restrict__ edge_dst,
                             int* __restrict__ cnt, int* __restrict__ seq) {
    int idx = blockIdx.x * blockDim.x + threadIdx.x;
    if (idx < EE) seq[idx] = atomicAdd(&cnt[edge_dst[idx]], 1);
}

// ---------------- block-scan helper ----------------
__device__ inline int block_excl_scan(int v, int t, int* total) {
    __shared__ int wsum[4];
    int lane = t & 63, wv = t >> 6;
    int inc = v;
    for (int off = 1; off < 64; off <<= 1) {
        int n = __shfl_up(inc, off);
        if (lane >= off) inc += n;
    }
    if (lane == 63) wsum[wv] = inc;
    __syncthreads();
    int off_w = 0;
    for (int w = 0; w < wv; w++) off_w += wsum[w];
    *total = wsum[0] + wsum[1] + wsum[2] + wsum[3];
    return off_w + inc - v;
}

// ---------------- scan A: per-block exclusive scan + dis ----------------
__global__ __launch_bounds__(256) void scanA_kernel(const int* __restrict__ cnt,
                                                    int* __restrict__ rowptr,
                                                    float* __restrict__ dis,
                                                    int* __restrict__ bsum) {
    int t = threadIdx.x;
    int i = blockIdx.x * 256 + t;
    int d = 0;
    if (i < NN) {
        d = cnt[i] + 1;                        // +1 self-loop
        dis[i] = rsqrtf((float)d);
    }
    int total;
    int excl = block_excl_scan(d, t, &total);
    if (i < NN) rowptr[i] = excl;
    if (t == 0) bsum[blockIdx.x] = total;
}

// ---------------- scan B: scan block sums ----------------
__global__ __launch_bounds__(256) void scanB_kernel(const int* __restrict__ bsum,
                                                    int* __restrict__ boff,
                                                    int* __restrict__ rowptr) {
    int t = threadIdx.x;
    int v = (t < SBLK) ? bsum[t] : 0;
    int total;
    int excl = block_excl_scan(v, t, &total);
    if (t < SBLK) boff[t] = excl;
    if (t == 0) rowptr[NN] = total;
}

// ---------------- scan C: add block offsets ----------------
__global__ __launch_bounds__(256) void scanC_kernel(int* __restrict__ rowptr,
                                                    const int* __restrict__ boff) {
    int i = blockIdx.x * 256 + threadIdx.x;
    if (i < NN) rowptr[i] += boff[blockIdx.x];
}

// ---------------- CSR fill: atomic-free scatter ----------------
__global__ void fill_kernel(const int* __restrict__ edge_src,
                            const int* __restrict__ edge_dst,
                            const float* __restrict__ dis,
                            const int* __restrict__ rowptr,
                            const int* __restrict__ seq,
                            int2* __restrict__ csr) {
    int idx = blockIdx.x * blockDim.x + threadIdx.x;
    if (idx < EE) {
        int s = edge_src[idx], d = edge_dst[idx];
        int pos = rowptr[d] + seq[idx];
        csr[pos] = make_int2(s, __float_as_int(dis[s] * dis[d]));
    } else if (idx < ETOT) {
        int n = idx - EE;
        float dn = dis[n];
        csr[rowptr[n + 1] - 1] = make_int2(n, __float_as_int(dn * dn));
    }
}

// ---------------- GEMM1: hb = bf16(x @ W1)  (bf16 MFMA 16x16x32) ----------------
__global__ __launch_bounds__(256) void gemm1_kernel(const float* __restrict__ x,
                                                    const float* __restrict__ W1,
                                                    ushort_t* __restrict__ hb) {
    __shared__ ushort_t xs[64 * 136];
    __shared__ ushort_t wt[128 * 136];
    int t = threadIdx.x;
    int row0 = blockIdx.x * 64;
    for (int i = 0; i < 8; i++) {
        int slot = t + i * 256;
        int r = slot >> 5, k4 = slot & 31;
        int gr = row0 + r;
        float4 v = (gr < NN) ? ((const float4*)x)[gr * 32 + k4]
                             : make_float4(0.f, 0.f, 0.f, 0.f);
        u16x4 bv = { f2bf(v.x), f2bf(v.y), f2bf(v.z), f2bf(v.w) };
        *(u16x4*)(&xs[r * 136 + k4 * 4]) = bv;
    }
    for (int i = 0; i < 16; i++) {
        int slot = t + i * 256;
        int k = slot >> 5, c4 = slot & 31;
        float4 v = ((const float4*)W1)[k * 32 + c4];
        wt[(c4 * 4 + 0) * 136 + k] = f2bf(v.x);
        wt[(c4 * 4 + 1) * 136 + k] = f2bf(v.y);
        wt[(c4 * 4 + 2) * 136 + k] = f2bf(v.z);
        wt[(c4 * 4 + 3) * 136 + k] = f2bf(v.w);
    }
    __syncthreads();

    int wave = t >> 6, lane = t & 63;
    int m = lane & 15, quad = lane >> 4;
    f32x4 acc[8];
    for (int ct = 0; ct < 8; ct++) acc[ct] = (f32x4)(0.0f);

    for (int ko = 0; ko < 4; ko++) {
        bf16x8 a = *(const bf16x8*)(&xs[(16 * wave + m) * 136 + ko * 32 + quad * 8]);
        for (int ct = 0; ct < 8; ct++) {
            bf16x8 b = *(const bf16x8*)(&wt[(ct * 16 + m) * 136 + ko * 32 + quad * 8]);
            acc[ct] = __builtin_amdgcn_mfma_f32_16x16x32_bf16(a, b, acc[ct], 0, 0, 0);
        }
    }
    for (int ct = 0; ct < 8; ct++) {
        int gcol = ct * 16 + m;
        for (int r = 0; r < 4; r++) {
            int grow = row0 + wave * 16 + quad * 4 + r;
            if (grow < NN) hb[grow * HH + gcol] = f2bf(acc[ct][r]);
        }
    }
}

// ---------------- agg1: h1b = bf16(relu(segsum(w * hb[src]) + b1)) -------------
__global__ __launch_bounds__(256) void agg1_kernel(const ushort_t* __restrict__ hb,
                                                   const int* __restrict__ rowptr,
                                                   const int2* __restrict__ csr,
                                                   const float* __restrict__ b1,
                                                   ushort_t* __restrict__ h1b) {
    int wave = threadIdx.x >> 6, lane = threadIdx.x & 63;
    int node = blockIdx.x * 4 + wave;
    if (node >= NN) return;
    int slot = lane >> 4, sub = lane & 15;
    int e0 = rowptr[node], e1 = rowptr[node + 1];
    float acc[8] = {0, 0, 0, 0, 0, 0, 0, 0};
    for (int e = e0 + slot; e < e1; e += 4) {
        int2 ent = csr[e];
        float w = __int_as_float(ent.y);
        u16x8 hv = *(const u16x8*)(hb + (size_t)ent.x * HH + sub * 8);
        for (int j = 0; j < 8; j++) acc[j] += w * bf2f(hv[j]);
    }
    for (int j = 0; j < 8; j++) {
        acc[j] += __shfl_xor(acc[j], 16);
        acc[j] += __shfl_xor(acc[j], 32);
    }
    if (slot == 0) {
        u16x8 o;
        for (int j = 0; j < 8; j++)
            o[j] = f2bf(fmaxf(acc[j] + b1[sub * 8 + j], 0.0f));
        *(u16x8*)(h1b + (size_t)node * HH + sub * 8) = o;
    }
}

// ---------------- GEMM2: h2 = h1b @ W2  (bf16 MFMA, 16 cols) ----------------
__global__ __launch_bounds__(256) void gemm2_kernel(const ushort_t* __restrict__ h1b,
                                                    const float* __restrict__ W2,
                                                    float* __restrict__ h2) {
    __shared__ ushort_t w2s[HH * CC];
    int t = threadIdx.x;
    for (int i = t; i < HH * CC; i += 256) w2s[i] = f2bf(W2[i]);
    __syncthreads();
    int wave = t >> 6, lane = t & 63;
    int m = lane & 15, quad = lane >> 4;
    int node0 = (blockIdx.x * 4 + wave) * 16;
    f32x4 acc = (f32x4)(0.0f);
    int arow = node0 + m;
    for (int ko = 0; ko < 4; ko++) {
        bf16x8 a = (bf16x8)(short)0;
        if (arow < NN)
            a = *(const bf16x8*)(h1b + (size_t)arow * HH + ko * 32 + quad * 8);
        bf16x8 b;
        for (int j = 0; j < 8; j++)
            b[j] = (short)w2s[(ko * 32 + quad * 8 + j) * CC + m];
        acc = __builtin_amdgcn_mfma_f32_16x16x32_bf16(a, b, acc, 0, 0, 0);
    }
    for (int r = 0; r < 4; r++) {
        int grow = node0 + quad * 4 + r;
        if (grow < NN) h2[grow * CC + m] = acc[r];
    }
}

// ---------------- agg2 + pool fused ----------------
__global__ void agg2pool_kernel(const float* __restrict__ h2,
                                const int* __restrict__ rowptr,
                                const int2* __restrict__ csr,
                                const float* __restrict__ b2,
                                const int* __restrict__ batch,
                                float* __restrict__ pooled) {
    int idx = blockIdx.x * blockDim.x + threadIdx.x;
    int node = idx >> 4, c = idx & 15;
    if (node >= NN) return;
    int e0 = rowptr[node], e1 = rowptr[node + 1];
    float acc = 0.0f;
    for (int e = e0; e < e1; e++) {
        int2 ent = csr[e];
        acc += __int_as_float(ent.y) * h2[(size_t)ent.x * CC + c];
    }
    atomicAdd(&pooled[batch[node] * CC + c], acc + b2[c]);
}

// ---------------- mean + log_softmax (counts via binary search on sorted batch) ----
__global__ void lsm_kernel(const float* __restrict__ pooled,
                           const int* __restrict__ batch,
                           float* __restrict__ out) {
    int idx = blockIdx.x * blockDim.x + threadIdx.x;
    int g = idx >> 4, c = idx & 15;
    if (g >= GG) return;
    int lo = 0, hi = NN;
    while (lo < hi) { int mid = (lo + hi) >> 1; if (batch[mid] < g) lo = mid + 1; else hi = mid; }
    int lo2 = lo, hi2 = NN;
    while (lo2 < hi2) { int mid = (lo2 + hi2) >> 1; if (batch[mid] < g + 1) lo2 = mid + 1; else hi2 = mid; }
    float cnt = (float)(lo2 - lo);
    float v = pooled[g * CC + c] / fmaxf(cnt, 1.0f);
    float m = v;
    for (int off = 8; off >= 1; off >>= 1) m = fmaxf(m, __shfl_xor(m, off, 16));
    float s = expf(v - m);
    for (int off = 8; off >= 1; off >>= 1) s += __shfl_xor(s, off, 16);
    out[g * CC + c] = v - m - logf(s);
}

extern "C" void kernel_launch(void* const* d_in, const int* in_sizes, int n_in,
                              void* d_out, int out_size, void* d_ws, size_t ws_size,
                              hipStream_t stream) {
    const float* x  = (const float*)d_in[0];
    const float* W1 = (const float*)d_in[1];
    const float* b1 = (const float*)d_in[2];
    const float* W2 = (const float*)d_in[3];
    const float* b2 = (const float*)d_in[4];
    const int* edge_src = (const int*)d_in[5];
    const int* edge_dst = (const int*)d_in[6];
    const int* batch    = (const int*)d_in[7];
    float* out = (float*)d_out;

    char* ws = (char*)d_ws;
    size_t off = 0;
    auto alloc = [&](size_t bytes) {
        void* p = ws + off;
        off += (bytes + 255) & ~size_t(255);
        return p;
    };
    int*   cnt     = (int*)  alloc(NN * 4);
    float* dis     = (float*)alloc(NN * 4);
    int*   rowptr  = (int*)  alloc((NN + 1) * 4);
    int*   seq     = (int*)  alloc(EE * 4);
    int*   bsum    = (int*)  alloc(SBLK * 4);
    int*   boff    = (int*)  alloc(SBLK * 4);
    int2*  csr     = (int2*) alloc((size_t)ETOT * 8);
    ushort_t* hb   = (ushort_t*)alloc((size_t)NN * HH * 2);
    ushort_t* h1b  = (ushort_t*)alloc((size_t)NN * HH * 2);
    float* h2      = (float*)alloc((size_t)NN * CC * 4);
    float* pooled  = (float*)alloc(GG * CC * 4);

    const int B = 256;
    init_kernel<<<(NN + B - 1) / B, B, 0, stream>>>(cnt, pooled);
    count_kernel<<<(EE + B - 1) / B, B, 0, stream>>>(edge_dst, cnt, seq);
    scanA_kernel<<<SBLK, B, 0, stream>>>(cnt, rowptr, dis, bsum);
    scanB_kernel<<<1, B, 0, stream>>>(bsum, boff, rowptr);
    scanC_kernel<<<SBLK, B, 0, stream>>>(rowptr, boff);
    fill_kernel<<<(ETOT + B - 1) / B, B, 0, stream>>>(edge_src, edge_dst, dis,
                                                      rowptr, seq, csr);
    gemm1_kernel<<<(NN + 63) / 64, B, 0, stream>>>(x, W1, hb);
    agg1_kernel<<<(NN + 3) / 4, B, 0, stream>>>(hb, rowptr, csr, b1, h1b);
    gemm2_kernel<<<(NN + 63) / 64, B, 0, stream>>>(h1b, W2, h2);
    agg2pool_kernel<<<(NN * CC + B - 1) / B, B, 0, stream>>>(h2, rowptr, csr, b2, batch, pooled);
    lsm_kernel<<<(GG * CC + B - 1) / B, B, 0, stream>>>(pooled, batch, out);
}

// Round 5
// 217.262 us; speedup vs baseline: 1.9313x; 1.0644x over previous
//
#include <hip/hip_runtime.h>
#include <hip/hip_bf16.h>

// GCN 2-layer + mean-pool + log_softmax on gfx950.
// R5: hb stored fp8 e4m3 (halves agg1's random line requests: 2.6M -> 1.3M),
//     agg2pool uses sorted-batch LDS segmented flush (800k -> ~100k atomics).

#define NN 50000
#define EE 600000
#define FIN 128
#define HH 128
#define CC 16
#define GG 500
#define ETOT (EE + NN)   // edges + self loops = 650000
#define SBLK 196         // ceil(NN/256) scan blocks

typedef unsigned short ushort_t;
typedef unsigned int uint_t;

typedef __attribute__((ext_vector_type(8))) short bf16x8;
typedef __attribute__((ext_vector_type(8))) ushort_t u16x8;
typedef __attribute__((ext_vector_type(4))) ushort_t u16x4;
typedef __attribute__((ext_vector_type(4))) float f32x4;
typedef __attribute__((ext_vector_type(2))) float f32x2;

__device__ inline ushort_t f2bf(float f) {
    uint_t u = __float_as_uint(f);
    u = (u + 0x7FFFu + ((u >> 16) & 1u)) >> 16;   // RNE
    return (ushort_t)u;
}
__device__ inline float bf2f(ushort_t b) {
    return __uint_as_float(((uint_t)b) << 16);
}

// ---------------- init ----------------
__global__ void init_kernel(int* cnt, float* pooled) {
    int i = blockIdx.x * blockDim.x + threadIdx.x;
    if (i < NN) cnt[i] = 0;
    if (i < GG * CC) pooled[i] = 0.0f;
}

// ---------------- count + per-edge slot (the single atomic pass) ----------------
__global__ void count_kernel(const int* __restrict__ edge_dst,
                             int* __restrict__ cnt, int* __restrict__ seq) {
    int idx = blockIdx.x * blockDim.x + threadIdx.x;
    if (idx < EE) seq[idx] = atomicAdd(&cnt[edge_dst[idx]], 1);
}

// ---------------- block-scan helper ----------------
__device__ inline int block_excl_scan(int v, int t, int* total) {
    __shared__ int wsum[4];
    int lane = t & 63, wv = t >> 6;
    int inc = v;
    for (int off = 1; off < 64; off <<= 1) {
        int n = __shfl_up(inc, off);
        if (lane >= off) inc += n;
    }
    if (lane == 63) wsum[wv] = inc;
    __syncthreads();
    int off_w = 0;
    for (int w = 0; w < wv; w++) off_w += wsum[w];
    *total = wsum[0] + wsum[1] + wsum[2] + wsum[3];
    return off_w + inc - v;
}

// ---------------- scan A ----------------
__global__ __launch_bounds__(256) void scanA_kernel(const int* __restrict__ cnt,
                                                    int* __restrict__ rowptr,
                                                    float* __restrict__ dis,
                                                    int* __restrict__ bsum) {
    int t = threadIdx.x;
    int i = blockIdx.x * 256 + t;
    int d = 0;
    if (i < NN) {
        d = cnt[i] + 1;                        // +1 self-loop
        dis[i] = rsqrtf((float)d);
    }
    int total;
    int excl = block_excl_scan(d, t, &total);
    if (i < NN) rowptr[i] = excl;
    if (t == 0) bsum[blockIdx.x] = total;
}

// ---------------- scan B ----------------
__global__ __launch_bounds__(256) void scanB_kernel(const int* __restrict__ bsum,
                                                    int* __restrict__ boff,
                                                    int* __restrict__ rowptr) {
    int t = threadIdx.x;
    int v = (t < SBLK) ? bsum[t] : 0;
    int total;
    int excl = block_excl_scan(v, t, &total);
    if (t < SBLK) boff[t] = excl;
    if (t == 0) rowptr[NN] = total;
}

// ---------------- scan C ----------------
__global__ __launch_bounds__(256) void scanC_kernel(int* __restrict__ rowptr,
                                                    const int* __restrict__ boff) {
    int i = blockIdx.x * 256 + threadIdx.x;
    if (i < NN) rowptr[i] += boff[blockIdx.x];
}

// ---------------- CSR fill: atomic-free scatter ----------------
__global__ void fill_kernel(const int* __restrict__ edge_src,
                            const int* __restrict__ edge_dst,
                            const float* __restrict__ dis,
                            const int* __restrict__ rowptr,
                            const int* __restrict__ seq,
                            int2* __restrict__ csr) {
    int idx = blockIdx.x * blockDim.x + threadIdx.x;
    if (idx < EE) {
        int s = edge_src[idx], d = edge_dst[idx];
        int pos = rowptr[d] + seq[idx];
        csr[pos] = make_int2(s, __float_as_int(dis[s] * dis[d]));
    } else if (idx < ETOT) {
        int n = idx - EE;
        float dn = dis[n];
        csr[rowptr[n + 1] - 1] = make_int2(n, __float_as_int(dn * dn));
    }
}

// ---------------- GEMM1: hb8 = fp8(x @ W1)  (bf16 MFMA 16x16x32) ----------------
__global__ __launch_bounds__(256) void gemm1_kernel(const float* __restrict__ x,
                                                    const float* __restrict__ W1,
                                                    unsigned char* __restrict__ hb8) {
    __shared__ ushort_t xs[64 * 136];
    __shared__ ushort_t wt[128 * 136];
    int t = threadIdx.x;
    int row0 = blockIdx.x * 64;
    for (int i = 0; i < 8; i++) {
        int slot = t + i * 256;
        int r = slot >> 5, k4 = slot & 31;
        int gr = row0 + r;
        float4 v = (gr < NN) ? ((const float4*)x)[gr * 32 + k4]
                             : make_float4(0.f, 0.f, 0.f, 0.f);
        u16x4 bv = { f2bf(v.x), f2bf(v.y), f2bf(v.z), f2bf(v.w) };
        *(u16x4*)(&xs[r * 136 + k4 * 4]) = bv;
    }
    for (int i = 0; i < 16; i++) {
        int slot = t + i * 256;
        int k = slot >> 5, c4 = slot & 31;
        float4 v = ((const float4*)W1)[k * 32 + c4];
        wt[(c4 * 4 + 0) * 136 + k] = f2bf(v.x);
        wt[(c4 * 4 + 1) * 136 + k] = f2bf(v.y);
        wt[(c4 * 4 + 2) * 136 + k] = f2bf(v.z);
        wt[(c4 * 4 + 3) * 136 + k] = f2bf(v.w);
    }
    __syncthreads();

    int wave = t >> 6, lane = t & 63;
    int m = lane & 15, quad = lane >> 4;
    f32x4 acc[8];
    for (int ct = 0; ct < 8; ct++) acc[ct] = (f32x4)(0.0f);

    for (int ko = 0; ko < 4; ko++) {
        bf16x8 a = *(const bf16x8*)(&xs[(16 * wave + m) * 136 + ko * 32 + quad * 8]);
        for (int ct = 0; ct < 8; ct++) {
            bf16x8 b = *(const bf16x8*)(&wt[(ct * 16 + m) * 136 + ko * 32 + quad * 8]);
            acc[ct] = __builtin_amdgcn_mfma_f32_16x16x32_bf16(a, b, acc[ct], 0, 0, 0);
        }
    }
    // D: col = lane&15, row = quad*4 + reg
    for (int ct = 0; ct < 8; ct++) {
        int gcol = ct * 16 + m;
        for (int r = 0; r < 4; r++) {
            int grow = row0 + wave * 16 + quad * 4 + r;
            if (grow < NN) {
                int p = __builtin_amdgcn_cvt_pk_fp8_f32(acc[ct][r], 0.0f, 0, false);
                hb8[(size_t)grow * HH + gcol] = (unsigned char)(p & 0xFF);
            }
        }
    }
}

// ---------------- agg1: h1b = bf16(relu(segsum(w * fp8row) + b1)) -------------
// 1 wave per node; 8 edge slots x 8 feature-lanes (16 fp8 = 16B/lane).
__global__ __launch_bounds__(256) void agg1_kernel(const unsigned char* __restrict__ hb8,
                                                   const int* __restrict__ rowptr,
                                                   const int2* __restrict__ csr,
                                                   const float* __restrict__ b1,
                                                   ushort_t* __restrict__ h1b) {
    int wave = threadIdx.x >> 6, lane = threadIdx.x & 63;
    int node = blockIdx.x * 4 + wave;
    if (node >= NN) return;
    int slot = lane >> 3, sub = lane & 7;
    int e0 = rowptr[node], e1 = rowptr[node + 1];
    float acc[16];
    for (int j = 0; j < 16; j++) acc[j] = 0.0f;
    for (int e = e0 + slot; e < e1; e += 8) {
        int2 ent = csr[e];
        float w = __int_as_float(ent.y);
        uint4 hv = *(const uint4*)(hb8 + (size_t)ent.x * HH + sub * 16);
        uint_t words[4] = { hv.x, hv.y, hv.z, hv.w };
        for (int q = 0; q < 4; q++) {
            f32x2 lo = __builtin_amdgcn_cvt_pk_f32_fp8(words[q], false);
            f32x2 hi = __builtin_amdgcn_cvt_pk_f32_fp8(words[q], true);
            acc[q * 4 + 0] += w * lo[0];
            acc[q * 4 + 1] += w * lo[1];
            acc[q * 4 + 2] += w * hi[0];
            acc[q * 4 + 3] += w * hi[1];
        }
    }
    // reduce the 8 slots (slot index is lane>>3 -> xor distances 8,16,32)
    for (int j = 0; j < 16; j++) {
        acc[j] += __shfl_xor(acc[j], 8);
        acc[j] += __shfl_xor(acc[j], 16);
        acc[j] += __shfl_xor(acc[j], 32);
    }
    if (slot == 0) {
        u16x8 o0, o1;
        for (int j = 0; j < 8; j++) {
            o0[j] = f2bf(fmaxf(acc[j]     + b1[sub * 16 + j],     0.0f));
            o1[j] = f2bf(fmaxf(acc[8 + j] + b1[sub * 16 + 8 + j], 0.0f));
        }
        *(u16x8*)(h1b + (size_t)node * HH + sub * 16)     = o0;
        *(u16x8*)(h1b + (size_t)node * HH + sub * 16 + 8) = o1;
    }
}

// ---------------- GEMM2: h2 = h1b @ W2  (bf16 MFMA, 16 cols) ----------------
__global__ __launch_bounds__(256) void gemm2_kernel(const ushort_t* __restrict__ h1b,
                                                    const float* __restrict__ W2,
                                                    float* __restrict__ h2) {
    __shared__ ushort_t w2s[HH * CC];
    int t = threadIdx.x;
    for (int i = t; i < HH * CC; i += 256) w2s[i] = f2bf(W2[i]);
    __syncthreads();
    int wave = t >> 6, lane = t & 63;
    int m = lane & 15, quad = lane >> 4;
    int node0 = (blockIdx.x * 4 + wave) * 16;
    f32x4 acc = (f32x4)(0.0f);
    int arow = node0 + m;
    for (int ko = 0; ko < 4; ko++) {
        bf16x8 a = (bf16x8)(short)0;
        if (arow < NN)
            a = *(const bf16x8*)(h1b + (size_t)arow * HH + ko * 32 + quad * 8);
        bf16x8 b;
        for (int j = 0; j < 8; j++)
            b[j] = (short)w2s[(ko * 32 + quad * 8 + j) * CC + m];
        acc = __builtin_amdgcn_mfma_f32_16x16x32_bf16(a, b, acc, 0, 0, 0);
    }
    for (int r = 0; r < 4; r++) {
        int grow = node0 + quad * 4 + r;
        if (grow < NN) h2[grow * CC + m] = acc[r];
    }
}

// ---------------- agg2 + pool fused, sorted-batch segmented flush ----------------
// 16 nodes/block (NN = 3125 * 16 exactly). Stage per-node results in LDS,
// 16 walker threads (one per channel) flush runs of equal batch id.
__global__ __launch_bounds__(256) void agg2pool_kernel(const float* __restrict__ h2,
                                                       const int* __restrict__ rowptr,
                                                       const int2* __restrict__ csr,
                                                       const float* __restrict__ b2,
                                                       const int* __restrict__ batch,
                                                       float* __restrict__ pooled) {
    __shared__ float vals[16][16];
    __shared__ int gid[16];
    int t = threadIdx.x;
    int local = t >> 4, c = t & 15;
    int node = blockIdx.x * 16 + local;
    int e0 = rowptr[node], e1 = rowptr[node + 1];
    float acc = 0.0f;
    for (int e = e0; e < e1; e++) {
        int2 ent = csr[e];
        acc += __int_as_float(ent.y) * h2[(size_t)ent.x * CC + c];
    }
    vals[local][c] = acc + b2[c];
    if (c == 0) gid[local] = batch[node];
    __syncthreads();
    if (t < 16) {                      // walker for channel t
        float run = 0.0f;
        for (int i = 0; i < 16; i++) {
            run += vals[i][t];
            if (i == 15 || gid[i + 1] != gid[i]) {
                atomicAdd(&pooled[gid[i] * CC + t], run);
                run = 0.0f;
            }
        }
    }
}

// ---------------- mean + log_softmax (counts via binary search) ----------------
__global__ void lsm_kernel(const float* __restrict__ pooled,
                           const int* __restrict__ batch,
                           float* __restrict__ out) {
    int idx = blockIdx.x * blockDim.x + threadIdx.x;
    int g = idx >> 4, c = idx & 15;
    if (g >= GG) return;
    int lo = 0, hi = NN;
    while (lo < hi) { int mid = (lo + hi) >> 1; if (batch[mid] < g) lo = mid + 1; else hi = mid; }
    int lo2 = lo, hi2 = NN;
    while (lo2 < hi2) { int mid = (lo2 + hi2) >> 1; if (batch[mid] < g + 1) lo2 = mid + 1; else hi2 = mid; }
    float cnt = (float)(lo2 - lo);
    float v = pooled[g * CC + c] / fmaxf(cnt, 1.0f);
    float m = v;
    for (int off = 8; off >= 1; off >>= 1) m = fmaxf(m, __shfl_xor(m, off, 16));
    float s = expf(v - m);
    for (int off = 8; off >= 1; off >>= 1) s += __shfl_xor(s, off, 16);
    out[g * CC + c] = v - m - logf(s);
}

extern "C" void kernel_launch(void* const* d_in, const int* in_sizes, int n_in,
                              void* d_out, int out_size, void* d_ws, size_t ws_size,
                              hipStream_t stream) {
    const float* x  = (const float*)d_in[0];
    const float* W1 = (const float*)d_in[1];
    const float* b1 = (const float*)d_in[2];
    const float* W2 = (const float*)d_in[3];
    const float* b2 = (const float*)d_in[4];
    const int* edge_src = (const int*)d_in[5];
    const int* edge_dst = (const int*)d_in[6];
    const int* batch    = (const int*)d_in[7];
    float* out = (float*)d_out;

    char* ws = (char*)d_ws;
    size_t off = 0;
    auto alloc = [&](size_t bytes) {
        void* p = ws + off;
        off += (bytes + 255) & ~size_t(255);
        return p;
    };
    int*   cnt     = (int*)  alloc(NN * 4);
    float* dis     = (float*)alloc(NN * 4);
    int*   rowptr  = (int*)  alloc((NN + 1) * 4);
    int*   seq     = (int*)  alloc(EE * 4);
    int*   bsum    = (int*)  alloc(SBLK * 4);
    int*   boff    = (int*)  alloc(SBLK * 4);
    int2*  csr     = (int2*) alloc((size_t)ETOT * 8);
    unsigned char* hb8 = (unsigned char*)alloc((size_t)NN * HH);
    ushort_t* h1b  = (ushort_t*)alloc((size_t)NN * HH * 2);
    float* h2      = (float*)alloc((size_t)NN * CC * 4);
    float* pooled  = (float*)alloc(GG * CC * 4);

    const int B = 256;
    init_kernel<<<(NN + B - 1) / B, B, 0, stream>>>(cnt, pooled);
    count_kernel<<<(EE + B - 1) / B, B, 0, stream>>>(edge_dst, cnt, seq);
    scanA_kernel<<<SBLK, B, 0, stream>>>(cnt, rowptr, dis, bsum);
    scanB_kernel<<<1, B, 0, stream>>>(bsum, boff, rowptr);
    scanC_kernel<<<SBLK, B, 0, stream>>>(rowptr, boff);
    fill_kernel<<<(ETOT + B - 1) / B, B, 0, stream>>>(edge_src, edge_dst, dis,
                                                      rowptr, seq, csr);
    gemm1_kernel<<<(NN + 63) / 64, B, 0, stream>>>(x, W1, hb8);
    agg1_kernel<<<(NN + 3) / 4, B, 0, stream>>>(hb8, rowptr, csr, b1, h1b);
    gemm2_kernel<<<(NN + 63) / 64, B, 0, stream>>>(h1b, W2, h2);
    agg2pool_kernel<<<NN / 16, B, 0, stream>>>(h2, rowptr, csr, b2, batch, pooled);
    lsm_kernel<<<(GG * CC + B - 1) / B, B, 0, stream>>>(pooled, batch, out);
}

// Round 6
// 211.420 us; speedup vs baseline: 1.9847x; 1.0276x over previous
//
#include <hip/hip_runtime.h>
#include <hip/hip_bf16.h>

// GCN 2-layer + mean-pool + log_softmax on gfx950.
// R6: normalization factorization A_hat = D^-1/2 (A+I) D^-1/2 — right diag
//     folded into GEMM epilogues (rows pre-scaled by dis[row]), left diag into
//     aggregation epilogues (x dis[node]). CSR = bare src index (4B, no
//     weight, no dis gathers in fill). h2 stored bf16. scanB+scanC merged.

#define NN 50000
#define EE 600000
#define FIN 128
#define HH 128
#define CC 16
#define GG 500
#define ETOT (EE + NN)   // edges + self loops = 650000
#define SBLK 196         // ceil(NN/256) scan blocks

typedef unsigned short ushort_t;
typedef unsigned int uint_t;

typedef __attribute__((ext_vector_type(8))) short bf16x8;
typedef __attribute__((ext_vector_type(8))) ushort_t u16x8;
typedef __attribute__((ext_vector_type(4))) ushort_t u16x4;
typedef __attribute__((ext_vector_type(4))) float f32x4;
typedef __attribute__((ext_vector_type(2))) float f32x2;

__device__ inline ushort_t f2bf(float f) {
    uint_t u = __float_as_uint(f);
    u = (u + 0x7FFFu + ((u >> 16) & 1u)) >> 16;   // RNE
    return (ushort_t)u;
}
__device__ inline float bf2f(ushort_t b) {
    return __uint_as_float(((uint_t)b) << 16);
}

// ---------------- init ----------------
__global__ void init_kernel(int* cnt, float* pooled) {
    int i = blockIdx.x * blockDim.x + threadIdx.x;
    if (i < NN) cnt[i] = 0;
    if (i < GG * CC) pooled[i] = 0.0f;
}

// ---------------- count + per-edge slot (the single atomic pass) ----------------
__global__ void count_kernel(const int* __restrict__ edge_dst,
                             int* __restrict__ cnt, int* __restrict__ seq) {
    int idx = blockIdx.x * blockDim.x + threadIdx.x;
    if (idx < EE) seq[idx] = atomicAdd(&cnt[edge_dst[idx]], 1);
}

// ---------------- block-scan helper ----------------
__device__ inline int block_excl_scan(int v, int t, int* total) {
    __shared__ int wsum[4];
    int lane = t & 63, wv = t >> 6;
    int inc = v;
    for (int off = 1; off < 64; off <<= 1) {
        int n = __shfl_up(inc, off);
        if (lane >= off) inc += n;
    }
    if (lane == 63) wsum[wv] = inc;
    __syncthreads();
    int off_w = 0;
    for (int w = 0; w < wv; w++) off_w += wsum[w];
    *total = wsum[0] + wsum[1] + wsum[2] + wsum[3];
    return off_w + inc - v;
}

// ---------------- scan A: per-block exclusive scan + dis ----------------
__global__ __launch_bounds__(256) void scanA_kernel(const int* __restrict__ cnt,
                                                    int* __restrict__ rowptr,
                                                    float* __restrict__ dis,
                                                    int* __restrict__ bsum) {
    int t = threadIdx.x;
    int i = blockIdx.x * 256 + t;
    int d = 0;
    if (i < NN) {
        d = cnt[i] + 1;                        // +1 self-loop
        dis[i] = rsqrtf((float)d);
    }
    int total;
    int excl = block_excl_scan(d, t, &total);
    if (i < NN) rowptr[i] = excl;
    if (t == 0) bsum[blockIdx.x] = total;
}

// ---------------- scan BC: every block scans the 196 block sums, adds own offset ----
__global__ __launch_bounds__(256) void scanBC_kernel(int* __restrict__ rowptr,
                                                     const int* __restrict__ bsum) {
    __shared__ int sb[256];
    int t = threadIdx.x;
    int v = (t < SBLK) ? bsum[t] : 0;
    int total;
    int ex = block_excl_scan(v, t, &total);
    sb[t] = ex;
    __syncthreads();
    int myoff = sb[blockIdx.x];
    int i = blockIdx.x * 256 + t;
    if (i < NN) rowptr[i] += myoff;
    if (blockIdx.x == 0 && t == 0) rowptr[NN] = ETOT;
}

// ---------------- CSR fill: atomic-free, bare src index ----------------
__global__ void fill_kernel(const int* __restrict__ edge_src,
                            const int* __restrict__ edge_dst,
                            const int* __restrict__ rowptr,
                            const int* __restrict__ seq,
                            int* __restrict__ csr) {
    int idx = blockIdx.x * blockDim.x + threadIdx.x;
    if (idx < EE) {
        int d = edge_dst[idx];
        csr[rowptr[d] + seq[idx]] = edge_src[idx];
    } else if (idx < ETOT) {
        int n = idx - EE;
        csr[rowptr[n + 1] - 1] = n;            // self-loop in last slot
    }
}

// ---------------- GEMM1: hb8 = fp8(dis[row] * (x @ W1)) ----------------
__global__ __launch_bounds__(256) void gemm1_kernel(const float* __restrict__ x,
                                                    const float* __restrict__ W1,
                                                    const float* __restrict__ dis,
                                                    unsigned char* __restrict__ hb8) {
    __shared__ ushort_t xs[64 * 136];
    __shared__ ushort_t wt[128 * 136];
    int t = threadIdx.x;
    int row0 = blockIdx.x * 64;
    for (int i = 0; i < 8; i++) {
        int slot = t + i * 256;
        int r = slot >> 5, k4 = slot & 31;
        int gr = row0 + r;
        float4 v = (gr < NN) ? ((const float4*)x)[gr * 32 + k4]
                             : make_float4(0.f, 0.f, 0.f, 0.f);
        u16x4 bv = { f2bf(v.x), f2bf(v.y), f2bf(v.z), f2bf(v.w) };
        *(u16x4*)(&xs[r * 136 + k4 * 4]) = bv;
    }
    for (int i = 0; i < 16; i++) {
        int slot = t + i * 256;
        int k = slot >> 5, c4 = slot & 31;
        float4 v = ((const float4*)W1)[k * 32 + c4];
        wt[(c4 * 4 + 0) * 136 + k] = f2bf(v.x);
        wt[(c4 * 4 + 1) * 136 + k] = f2bf(v.y);
        wt[(c4 * 4 + 2) * 136 + k] = f2bf(v.z);
        wt[(c4 * 4 + 3) * 136 + k] = f2bf(v.w);
    }
    __syncthreads();

    int wave = t >> 6, lane = t & 63;
    int m = lane & 15, quad = lane >> 4;
    f32x4 acc[8];
    for (int ct = 0; ct < 8; ct++) acc[ct] = (f32x4)(0.0f);

    for (int ko = 0; ko < 4; ko++) {
        bf16x8 a = *(const bf16x8*)(&xs[(16 * wave + m) * 136 + ko * 32 + quad * 8]);
        for (int ct = 0; ct < 8; ct++) {
            bf16x8 b = *(const bf16x8*)(&wt[(ct * 16 + m) * 136 + ko * 32 + quad * 8]);
            acc[ct] = __builtin_amdgcn_mfma_f32_16x16x32_bf16(a, b, acc[ct], 0, 0, 0);
        }
    }
    // D: col = lane&15, row = quad*4 + reg
    float dsc[4];
    for (int r = 0; r < 4; r++) {
        int grow = row0 + wave * 16 + quad * 4 + r;
        dsc[r] = (grow < NN) ? dis[grow] : 0.0f;
    }
    for (int ct = 0; ct < 8; ct++) {
        int gcol = ct * 16 + m;
        for (int r = 0; r < 4; r++) {
            int grow = row0 + wave * 16 + quad * 4 + r;
            if (grow < NN) {
                int p = __builtin_amdgcn_cvt_pk_fp8_f32(acc[ct][r] * dsc[r], 0.0f, 0, false);
                hb8[(size_t)grow * HH + gcol] = (unsigned char)(p & 0xFF);
            }
        }
    }
}

// ---------------- agg1: h1b = bf16(relu(dis[node] * segsum(fp8row) + b1)) ------
// 1 wave per node; 8 edge slots x 8 feature-lanes (16 fp8 = 16B/lane).
__global__ __launch_bounds__(256) void agg1_kernel(const unsigned char* __restrict__ hb8,
                                                   const int* __restrict__ rowptr,
                                                   const int* __restrict__ csr,
                                                   const float* __restrict__ dis,
                                                   const float* __restrict__ b1,
                                                   ushort_t* __restrict__ h1b) {
    int wave = threadIdx.x >> 6, lane = threadIdx.x & 63;
    int node = blockIdx.x * 4 + wave;
    if (node >= NN) return;
    int slot = lane >> 3, sub = lane & 7;
    int e0 = rowptr[node], e1 = rowptr[node + 1];
    float acc[16];
    for (int j = 0; j < 16; j++) acc[j] = 0.0f;
    for (int e = e0 + slot; e < e1; e += 8) {
        int s = csr[e];
        uint4 hv = *(const uint4*)(hb8 + (size_t)s * HH + sub * 16);
        uint_t words[4] = { hv.x, hv.y, hv.z, hv.w };
        for (int q = 0; q < 4; q++) {
            f32x2 lo = __builtin_amdgcn_cvt_pk_f32_fp8(words[q], false);
            f32x2 hi = __builtin_amdgcn_cvt_pk_f32_fp8(words[q], true);
            acc[q * 4 + 0] += lo[0];
            acc[q * 4 + 1] += lo[1];
            acc[q * 4 + 2] += hi[0];
            acc[q * 4 + 3] += hi[1];
        }
    }
    for (int j = 0; j < 16; j++) {
        acc[j] += __shfl_xor(acc[j], 8);
        acc[j] += __shfl_xor(acc[j], 16);
        acc[j] += __shfl_xor(acc[j], 32);
    }
    if (slot == 0) {
        float dn = dis[node];
        u16x8 o0, o1;
        for (int j = 0; j < 8; j++) {
            o0[j] = f2bf(fmaxf(acc[j]     * dn + b1[sub * 16 + j],     0.0f));
            o1[j] = f2bf(fmaxf(acc[8 + j] * dn + b1[sub * 16 + 8 + j], 0.0f));
        }
        *(u16x8*)(h1b + (size_t)node * HH + sub * 16)     = o0;
        *(u16x8*)(h1b + (size_t)node * HH + sub * 16 + 8) = o1;
    }
}

// ---------------- GEMM2: h2b = bf16(dis[row] * (h1b @ W2)) ----------------
__global__ __launch_bounds__(256) void gemm2_kernel(const ushort_t* __restrict__ h1b,
                                                    const float* __restrict__ W2,
                                                    const float* __restrict__ dis,
                                                    ushort_t* __restrict__ h2b) {
    __shared__ ushort_t w2s[HH * CC];
    int t = threadIdx.x;
    for (int i = t; i < HH * CC; i += 256) w2s[i] = f2bf(W2[i]);
    __syncthreads();
    int wave = t >> 6, lane = t & 63;
    int m = lane & 15, quad = lane >> 4;
    int node0 = (blockIdx.x * 4 + wave) * 16;
    f32x4 acc = (f32x4)(0.0f);
    int arow = node0 + m;
    for (int ko = 0; ko < 4; ko++) {
        bf16x8 a = (bf16x8)(short)0;
        if (arow < NN)
            a = *(const bf16x8*)(h1b + (size_t)arow * HH + ko * 32 + quad * 8);
        bf16x8 b;
        for (int j = 0; j < 8; j++)
            b[j] = (short)w2s[(ko * 32 + quad * 8 + j) * CC + m];
        acc = __builtin_amdgcn_mfma_f32_16x16x32_bf16(a, b, acc, 0, 0, 0);
    }
    for (int r = 0; r < 4; r++) {
        int grow = node0 + quad * 4 + r;
        if (grow < NN) h2b[grow * CC + m] = f2bf(acc[r] * dis[grow]);
    }
}

// ---------------- agg2 + pool fused, sorted-batch segmented flush ----------------
__global__ __launch_bounds__(256) void agg2pool_kernel(const ushort_t* __restrict__ h2b,
                                                       const int* __restrict__ rowptr,
                                                       const int* __restrict__ csr,
                                                       const float* __restrict__ dis,
                                                       const float* __restrict__ b2,
                                                       const int* __restrict__ batch,
                                                       float* __restrict__ pooled) {
    __shared__ float vals[16][16];
    __shared__ int gid[16];
    int t = threadIdx.x;
    int local = t >> 4, c = t & 15;
    int node = blockIdx.x * 16 + local;
    int e0 = rowptr[node], e1 = rowptr[node + 1];
    float acc = 0.0f;
    for (int e = e0; e < e1; e++) {
        acc += bf2f(h2b[(size_t)csr[e] * CC + c]);
    }
    vals[local][c] = acc * dis[node] + b2[c];
    if (c == 0) gid[local] = batch[node];
    __syncthreads();
    if (t < 16) {                      // walker for channel t
        float run = 0.0f;
        for (int i = 0; i < 16; i++) {
            run += vals[i][t];
            if (i == 15 || gid[i + 1] != gid[i]) {
                atomicAdd(&pooled[gid[i] * CC + t], run);
                run = 0.0f;
            }
        }
    }
}

// ---------------- mean + log_softmax (counts via binary search) ----------------
__global__ void lsm_kernel(const float* __restrict__ pooled,
                           const int* __restrict__ batch,
                           float* __restrict__ out) {
    int idx = blockIdx.x * blockDim.x + threadIdx.x;
    int g = idx >> 4, c = idx & 15;
    if (g >= GG) return;
    int lo = 0, hi = NN;
    while (lo < hi) { int mid = (lo + hi) >> 1; if (batch[mid] < g) lo = mid + 1; else hi = mid; }
    int lo2 = lo, hi2 = NN;
    while (lo2 < hi2) { int mid = (lo2 + hi2) >> 1; if (batch[mid] < g + 1) lo2 = mid + 1; else hi2 = mid; }
    float cnt = (float)(lo2 - lo);
    float v = pooled[g * CC + c] / fmaxf(cnt, 1.0f);
    float m = v;
    for (int off = 8; off >= 1; off >>= 1) m = fmaxf(m, __shfl_xor(m, off, 16));
    float s = expf(v - m);
    for (int off = 8; off >= 1; off >>= 1) s += __shfl_xor(s, off, 16);
    out[g * CC + c] = v - m - logf(s);
}

extern "C" void kernel_launch(void* const* d_in, const int* in_sizes, int n_in,
                              void* d_out, int out_size, void* d_ws, size_t ws_size,
                              hipStream_t stream) {
    const float* x  = (const float*)d_in[0];
    const float* W1 = (const float*)d_in[1];
    const float* b1 = (const float*)d_in[2];
    const float* W2 = (const float*)d_in[3];
    const float* b2 = (const float*)d_in[4];
    const int* edge_src = (const int*)d_in[5];
    const int* edge_dst = (const int*)d_in[6];
    const int* batch    = (const int*)d_in[7];
    float* out = (float*)d_out;

    char* ws = (char*)d_ws;
    size_t off = 0;
    auto alloc = [&](size_t bytes) {
        void* p = ws + off;
        off += (bytes + 255) & ~size_t(255);
        return p;
    };
    int*   cnt     = (int*)  alloc(NN * 4);
    float* dis     = (float*)alloc(NN * 4);
    int*   rowptr  = (int*)  alloc((NN + 1) * 4);
    int*   seq     = (int*)  alloc(EE * 4);
    int*   bsum    = (int*)  alloc(SBLK * 4);
    int*   csr     = (int*)  alloc((size_t)ETOT * 4);
    unsigned char* hb8 = (unsigned char*)alloc((size_t)NN * HH);
    ushort_t* h1b  = (ushort_t*)alloc((size_t)NN * HH * 2);
    ushort_t* h2b  = (ushort_t*)alloc((size_t)NN * CC * 2);
    float* pooled  = (float*)alloc(GG * CC * 4);

    const int B = 256;
    init_kernel<<<(NN + B - 1) / B, B, 0, stream>>>(cnt, pooled);
    count_kernel<<<(EE + B - 1) / B, B, 0, stream>>>(edge_dst, cnt, seq);
    scanA_kernel<<<SBLK, B, 0, stream>>>(cnt, rowptr, dis, bsum);
    scanBC_kernel<<<SBLK, B, 0, stream>>>(rowptr, bsum);
    fill_kernel<<<(ETOT + B - 1) / B, B, 0, stream>>>(edge_src, edge_dst, rowptr, seq, csr);
    gemm1_kernel<<<(NN + 63) / 64, B, 0, stream>>>(x, W1, dis, hb8);
    agg1_kernel<<<(NN + 3) / 4, B, 0, stream>>>(hb8, rowptr, csr, dis, b1, h1b);
    gemm2_kernel<<<(NN + 63) / 64, B, 0, stream>>>(h1b, W2, dis, h2b);
    agg2pool_kernel<<<NN / 16, B, 0, stream>>>(h2b, rowptr, csr, dis, b2, batch, pooled);
    lsm_kernel<<<(GG * CC + B - 1) / B, B, 0, stream>>>(pooled, batch, out);
}